// Round 4
// baseline (196.555 us; speedup 1.0000x reference)
//
#include <hip/hip_runtime.h>
#include <math.h>

#define BATCH 65536
#define LHIST 128
#define HFUT  32
#define CH    16            // history chunk length (steps per staging burst)
#define PITCH 20            // LDS tile row pitch in floats (bank-spread: gcd(5,8)=1)
#define TILE  (64 * PITCH)  // 1280 floats: one [64 rows x 16 cols] array tile
#define BUFSZ (3 * TILE)    // v, dt, y tiles for one chunk

__device__ __forceinline__ float softplusf(float x) {
    // log(1+e^x), numerically stable; matches jax.nn.softplus (uniform, runs once)
    return fmaxf(x, 0.0f) + log1pf(expf(-fabsf(x)));
}

// 65536 threads = 1024 waves = structurally 1 wave/SIMD. Baseline analysis:
// FETCH == input bytes but only 2.1 TB/s -- REQUEST-RATE bound (row-per-thread
// layout scatters each wave-load into 64 distinct lines, 16B/request).
// This version stages each chunk with 4-lane-coalesced loads (lanes 4m..4m+3
// read one row's contiguous 64B -> 4x fewer, 4x larger requests) and
// lane-exchanges through a wave-private LDS tile. Registers double-buffer in
// TIME (next chunk's 12 float4s in flight during current chunk's compute);
// LDS is only the lane-exchange medium -> single buffer, no barriers, no asm.
__global__ __launch_bounds__(256, 1) void kalman_fwd(
    const float* __restrict__ v_hist,
    const float* __restrict__ dt_hist,
    const float* __restrict__ x_obs,
    const float* __restrict__ v_fut,
    const float* __restrict__ dt_fut,
    const float* __restrict__ theta,
    float* __restrict__ out)
{
    const int tid  = threadIdx.x;
    const int b    = blockIdx.x * 256 + tid;
    const int lane = tid & 63;
    const int wid  = tid >> 6;
    const int b0   = blockIdx.x * 256 + wid * 64;   // wave's first batch row

    __shared__ __align__(16) float lds[4 * BUFSZ];  // 60 KiB, wave-private slices
    float* wl = &lds[wid * BUFSZ];

    // ---- uniform parameter transforms (once per thread, wave-uniform) ----
    const float alpha = 1.0f / (1.0f + expf(-theta[0]));
    const float c     = softplusf(theta[1]);
    const float kappa = softplusf(theta[2]);
    const float vc    = softplusf(theta[3]);       // VC_MIN = 0
    const float qx    = expf(theta[4]);
    const float qu    = expf(theta[5]);
    const float Rn    = expf(theta[6]);
    const float qs    = expf(theta[7]);
    const float p0xx  = expf(theta[8]);
    const float p0uu  = expf(theta[9]);
    const float a1    = softplusf(theta[10]);
    const float d1    = softplusf(theta[11]);
    const float d2    = softplusf(theta[12]);
    const float d3    = softplusf(theta[13]);
    const float b1    = theta[14];
    const float b2    = theta[15];
    const float beta  = theta[16];
    const float rho_m = tanhf(theta[17]);
    const float qm    = expf(theta[18]);
    const float p0mm  = expf(theta[19]);
    const float vc2   = vc * vc;
    const float qxs   = qs * qx;
    const float qus   = qs * qu;
    const float rm2   = rho_m * rho_m;
    const float nal2e = -alpha * 1.44269504088896340736f;  // exp(-a*dt)=exp2(nal2e*dt)

    // ---- per-thread state: s = (x,u,m); P symmetric 3x3 (6 uniques) ----
    float sx = 0.0f, su = 0.0f, sm = 0.0f;
    float p00 = p0xx, p01 = 0.0f, p02 = 0.0f, p11 = p0uu, p12 = 0.0f, p22 = p0mm;

    auto predict = [&](float v, float dv, float dt_raw) {
        float dt  = fmaxf(dt_raw, 1e-6f);
        float rho = __builtin_amdgcn_exp2f(nal2e * dt);
        float forcing = fmaxf(v * v - vc2, 0.0f);
        float cl = -a1 * su + b1 * v + b2 * dv
                 - d1 * su * su - d2 * su * fabsf(v) - d3 * su * fabsf(su);
        float kdt = kappa * dt;
        float x_p = sx + su * dt;
        float u_p = rho * su - kdt * sx + c * forcing * dt + cl * dt + beta * sm;
        float m_p = rho_m * sm;
        float f0 = p00 + dt * p01;
        float f1 = p01 + dt * p11;
        float f2 = p02 + dt * p12;
        float g0 = -kdt * p00 + rho * p01 + beta * p02;
        float g1 = -kdt * p01 + rho * p11 + beta * p12;
        float g2 = -kdt * p02 + rho * p12 + beta * p22;
        float n00 = f0 + dt * f1 + qxs * dt;
        float n01 = -kdt * f0 + rho * f1 + beta * f2;
        float n02 = rho_m * f2;
        float n11 = -kdt * g0 + rho * g1 + beta * g2 + qus * dt;
        float n12 = rho_m * g2;
        float n22 = rm2 * p22 + qm;
        sx = x_p; su = u_p; sm = m_p;
        p00 = n00; p01 = n01; p02 = n02; p11 = n11; p12 = n12; p22 = n22;
    };

    auto update = [&](float y) {
        float innov = y - sx;
        float S    = p00 + Rn;
        float Sinv = __builtin_amdgcn_rcpf(S);
        float K0 = p00 * Sinv, K1 = p01 * Sinv, K2 = p02 * Sinv;
        sx += K0 * innov; su += K1 * innov; sm += K2 * innov;
        float a = 1.0f - K0;
        float n00 = a * a * p00 + Rn * K0 * K0;
        float n01 = a * (p01 - K1 * p00) + Rn * K0 * K1;
        float n02 = a * (p02 - K2 * p00) + Rn * K0 * K2;
        float n11 = S * K1 * K1 - 2.0f * K1 * p01 + p11;
        float n12 = S * K1 * K2 - K2 * p01 - K1 * p02 + p12;
        float n22 = S * K2 * K2 - 2.0f * K2 * p02 + p22;
        p00 = n00; p01 = n01; p02 = n02; p11 = n11; p12 = n12; p22 = n22;
    };

    // ---- coalesced staging addressing ----
    // load instr i (0..3), lane L: row = b0 + i*16 + (L>>2), cols k*16 + (L&3)*4 ..+4
    // -> lanes 4m..4m+3 read one row's contiguous 64B (one 64B request, not 4x16B)
    const int    srow = b0 + (lane >> 2);
    const int    scol = (lane & 3) * 4;
    const float* gv = v_hist  + (size_t)srow * LHIST + scol;
    const float* gd = dt_hist + (size_t)srow * LHIST + scol;
    const float* gy = x_obs   + (size_t)srow * LHIST + scol;
    // LDS write: tile row r = i*16 + (L>>2) at r*PITCH + (L&3)*4
    float*       lw = wl + (lane >> 2) * PITCH + scol;
    // LDS read: lane reads its own row (global row b0+lane == b)
    const float* lr = wl + lane * PITCH;

    float4 sv[4], sd[4], sy[4];           // one chunk in flight (48 VGPRs)

    auto issue_loads = [&](int k) {
        #pragma unroll
        for (int i = 0; i < 4; ++i) {
            sv[i] = *(const float4*)(gv + (size_t)i * 16 * LHIST + k * CH);
            sd[i] = *(const float4*)(gd + (size_t)i * 16 * LHIST + k * CH);
            sy[i] = *(const float4*)(gy + (size_t)i * 16 * LHIST + k * CH);
        }
    };
    auto write_stage = [&]() {
        #pragma unroll
        for (int i = 0; i < 4; ++i) {
            *(float4*)(lw + 0 * TILE + i * 16 * PITCH) = sv[i];
            *(float4*)(lw + 1 * TILE + i * 16 * PITCH) = sd[i];
            *(float4*)(lw + 2 * TILE + i * 16 * PITCH) = sy[i];
        }
    };

    // rolling v-carry: vp1 = v[t'-1], vp2 = v[t'-2]; step t' does
    // predict(v[t'-1], v[t'-1]-v[t'-2], dt[t']); update(y[t'])  (t' = t+1)
    float vp1 = 0.0f, vp2 = 0.0f;

    auto do_group = [&](int g) {            // 4 steps from LDS group g
        float4 v4 = *(const float4*)(lr + 0 * TILE + g * 4);
        float4 d4 = *(const float4*)(lr + 1 * TILE + g * 4);
        float4 y4 = *(const float4*)(lr + 2 * TILE + g * 4);
        const float* vv = (const float*)&v4;
        const float* dd = (const float*)&d4;
        const float* yy = (const float*)&y4;
        #pragma unroll
        for (int m = 0; m < 4; ++m) {
            float vcur = vv[m];
            predict(vp1, vp1 - vp2, dd[m]);
            update(yy[m]);
            vp2 = vp1; vp1 = vcur;
        }
    };

    // ---- prologue: chunk 0 staged, chunk 1 in flight ----
    issue_loads(0);
    write_stage();                           // vmcnt wait inserted by compiler
    issue_loads(1);
    __builtin_amdgcn_sched_barrier(0);

    // ---- chunk 0: t' = 0 consumed as init (sx = y[0], dv(1)=0), then t'=1..15
    {
        float4 v4 = *(const float4*)(lr + 0 * TILE);
        float4 d4 = *(const float4*)(lr + 1 * TILE);
        float4 y4 = *(const float4*)(lr + 2 * TILE);
        const float* vv = (const float*)&v4;
        const float* dd = (const float*)&d4;
        const float* yy = (const float*)&y4;
        sx = yy[0]; vp1 = vv[0]; vp2 = vv[0];
        #pragma unroll
        for (int m = 1; m < 4; ++m) {
            float vcur = vv[m];
            predict(vp1, vp1 - vp2, dd[m]);
            update(yy[m]);
            vp2 = vp1; vp1 = vcur;
        }
        #pragma unroll
        for (int g = 1; g < 4; ++g) do_group(g);
    }

    // ---- chunks 1..6: write staged chunk, issue next, compute (branch-free body)
    #pragma unroll 1
    for (int k = 1; k < 7; ++k) {
        write_stage();                       // waits on chunk k's loads (counted)
        issue_loads(k + 1);                  // chunk k+1 in flight under compute k
        __builtin_amdgcn_sched_barrier(0);
        #pragma unroll
        for (int g = 0; g < 4; ++g) do_group(g);
    }

    // ---- chunk 7: future inputs prefetched under its compute ----
    float vf[HFUT], df[HFUT];
    {
        write_stage();
        const float4* vf4 = (const float4*)(v_fut  + (size_t)b * HFUT);
        const float4* df4 = (const float4*)(dt_fut + (size_t)b * HFUT);
        float4* VF = (float4*)vf; float4* DF = (float4*)df;
        #pragma unroll
        for (int i = 0; i < HFUT / 4; ++i) { VF[i] = vf4[i]; DF[i] = df4[i]; }
        __builtin_amdgcn_sched_barrier(0);
        #pragma unroll
        for (int g = 0; g < 4; ++g) do_group(g);
    }
    // history done: 127 predict/update pairs; vp1 = v_hist[b][127]

    // ---- future rollout: 32 predicts, outputs staged in registers ----
    float oxp[HFUT], oxv[HFUT], oue[HFUT];
    float vp = vp1;
    #pragma unroll
    for (int j = 0; j < HFUT; ++j) {
        predict(vf[j], vf[j] - vp, df[j]);
        vp = vf[j];
        oxp[j] = sx; oxv[j] = p00; oue[j] = su;
    }

    // ---- back-to-back full-line burst stores (measured-ideal WRITE_SIZE) ----
    float4* xp = (float4*)(out + (size_t)b * HFUT);
    float4* xv = (float4*)(out + (size_t)BATCH * HFUT + (size_t)b * HFUT);
    float4* ue = (float4*)(out + 2 * (size_t)BATCH * HFUT + (size_t)b * HFUT);
    float4* OXP = (float4*)oxp; float4* OXV = (float4*)oxv; float4* OUE = (float4*)oue;
    #pragma unroll
    for (int i = 0; i < HFUT / 4; ++i) {
        xp[i] = OXP[i]; xv[i] = OXV[i]; ue[i] = OUE[i];
    }
}

extern "C" void kernel_launch(void* const* d_in, const int* in_sizes, int n_in,
                              void* d_out, int out_size, void* d_ws, size_t ws_size,
                              hipStream_t stream) {
    const float* v_hist  = (const float*)d_in[0];
    const float* dt_hist = (const float*)d_in[1];
    const float* x_obs   = (const float*)d_in[2];
    const float* v_fut   = (const float*)d_in[3];
    const float* dt_fut  = (const float*)d_in[4];
    const float* theta   = (const float*)d_in[5];
    float* out = (float*)d_out;

    dim3 grid(BATCH / 256), block(256);
    hipLaunchKernelGGL(kalman_fwd, grid, block, 0, stream,
                       v_hist, dt_hist, x_obs, v_fut, dt_fut, theta, out);
}

// Round 6
// 189.981 us; speedup vs baseline: 1.0346x; 1.0346x over previous
//
#include <hip/hip_runtime.h>
#include <math.h>

#define BATCH 65536
#define LHIST 128
#define HFUT  32
#define CH    16            // history chunk length (steps per staging burst)
#define PITCH 20            // LDS tile row pitch in floats (16B-aligned rows)
#define TILE  (64 * PITCH)  // 1280 floats: one [64 rows x 16 cols] array tile
#define BUFSZ (3 * TILE)    // v, dt, y tiles for one chunk

__device__ __forceinline__ float softplusf(float x) {
    // log(1+e^x), numerically stable; matches jax.nn.softplus (uniform, runs once)
    return fmaxf(x, 0.0f) + log1pf(expf(-fabsf(x)));
}

// 65536 threads = 1024 waves = structurally 1 wave/SIMD: no TLP, all hiding
// must be in-wave. History staging: lanes 4m..4m+3 read one row's contiguous
// 64B (4x fewer, 4x larger requests than row-per-thread float4 scatter), then
// lane-exchange through a wave-private LDS tile. Registers hold ONE chunk in
// flight (48 VGPR) -- the time buffer; LDS is only the exchange medium.
// r4 lesson: NO register staging of the future phase (160 regs -> 52MB spill);
// rollout loads/stores stream directly, per 4-step group.
__global__ __launch_bounds__(256, 1) void kalman_fwd(
    const float* __restrict__ v_hist,
    const float* __restrict__ dt_hist,
    const float* __restrict__ x_obs,
    const float* __restrict__ v_fut,
    const float* __restrict__ dt_fut,
    const float* __restrict__ theta,
    float* __restrict__ out)
{
    const int tid  = threadIdx.x;
    const int b    = blockIdx.x * 256 + tid;
    const int lane = tid & 63;
    const int wid  = tid >> 6;
    const int b0   = blockIdx.x * 256 + wid * 64;   // wave's first batch row

    __shared__ __align__(16) float lds[4 * BUFSZ];  // 60 KiB, wave-private slices
    float* wl = &lds[wid * BUFSZ];

    // ---- uniform parameter transforms (once per thread, wave-uniform) ----
    const float alpha = 1.0f / (1.0f + expf(-theta[0]));
    const float c     = softplusf(theta[1]);
    const float kappa = softplusf(theta[2]);
    const float vc    = softplusf(theta[3]);       // VC_MIN = 0
    const float qx    = expf(theta[4]);
    const float qu    = expf(theta[5]);
    const float Rn    = expf(theta[6]);
    const float qs    = expf(theta[7]);
    const float p0xx  = expf(theta[8]);
    const float p0uu  = expf(theta[9]);
    const float a1    = softplusf(theta[10]);
    const float d1    = softplusf(theta[11]);
    const float d2    = softplusf(theta[12]);
    const float d3    = softplusf(theta[13]);
    const float b1    = theta[14];
    const float b2    = theta[15];
    const float beta  = theta[16];
    const float rho_m = tanhf(theta[17]);
    const float qm    = expf(theta[18]);
    const float p0mm  = expf(theta[19]);
    const float vc2   = vc * vc;
    const float qxs   = qs * qx;
    const float qus   = qs * qu;
    const float rm2   = rho_m * rho_m;
    const float nal2e = -alpha * 1.44269504088896340736f;  // exp(-a*dt)=exp2(nal2e*dt)

    // ---- per-thread state: s = (x,u,m); P symmetric 3x3 (6 uniques) ----
    float sx = 0.0f, su = 0.0f, sm = 0.0f;
    float p00 = p0xx, p01 = 0.0f, p02 = 0.0f, p11 = p0uu, p12 = 0.0f, p22 = p0mm;

    auto predict = [&](float v, float dv, float dt_raw) {
        float dt  = fmaxf(dt_raw, 1e-6f);
        float rho = __builtin_amdgcn_exp2f(nal2e * dt);
        float forcing = fmaxf(v * v - vc2, 0.0f);
        float cl = -a1 * su + b1 * v + b2 * dv
                 - d1 * su * su - d2 * su * fabsf(v) - d3 * su * fabsf(su);
        float kdt = kappa * dt;
        float x_p = sx + su * dt;
        float u_p = rho * su - kdt * sx + c * forcing * dt + cl * dt + beta * sm;
        float m_p = rho_m * sm;
        float f0 = p00 + dt * p01;
        float f1 = p01 + dt * p11;
        float f2 = p02 + dt * p12;
        float g0 = -kdt * p00 + rho * p01 + beta * p02;
        float g1 = -kdt * p01 + rho * p11 + beta * p12;
        float g2 = -kdt * p02 + rho * p12 + beta * p22;
        float n00 = f0 + dt * f1 + qxs * dt;
        float n01 = -kdt * f0 + rho * f1 + beta * f2;
        float n02 = rho_m * f2;
        float n11 = -kdt * g0 + rho * g1 + beta * g2 + qus * dt;
        float n12 = rho_m * g2;
        float n22 = rm2 * p22 + qm;
        sx = x_p; su = u_p; sm = m_p;
        p00 = n00; p01 = n01; p02 = n02; p11 = n11; p12 = n12; p22 = n22;
    };

    auto update = [&](float y) {
        float innov = y - sx;
        float S    = p00 + Rn;
        float Sinv = __builtin_amdgcn_rcpf(S);
        float K0 = p00 * Sinv, K1 = p01 * Sinv, K2 = p02 * Sinv;
        sx += K0 * innov; su += K1 * innov; sm += K2 * innov;
        float a = 1.0f - K0;
        float n00 = a * a * p00 + Rn * K0 * K0;
        float n01 = a * (p01 - K1 * p00) + Rn * K0 * K1;
        float n02 = a * (p02 - K2 * p00) + Rn * K0 * K2;
        float n11 = S * K1 * K1 - 2.0f * K1 * p01 + p11;
        float n12 = S * K1 * K2 - K2 * p01 - K1 * p02 + p12;
        float n22 = S * K2 * K2 - 2.0f * K2 * p02 + p22;
        p00 = n00; p01 = n01; p02 = n02; p11 = n11; p12 = n12; p22 = n22;
    };

    // ---- coalesced staging addressing ----
    // load instr i (0..3), lane L: row = b0 + i*16 + (L>>2), cols k*16 + (L&3)*4 ..+4
    // -> lanes 4m..4m+3 read one row's contiguous 64B (one 64B request)
    const int    srow = b0 + (lane >> 2);
    const int    scol = (lane & 3) * 4;
    const float* gv = v_hist  + (size_t)srow * LHIST + scol;
    const float* gd = dt_hist + (size_t)srow * LHIST + scol;
    const float* gy = x_obs   + (size_t)srow * LHIST + scol;
    // LDS write: tile row r = i*16 + (L>>2) at r*PITCH + (L&3)*4
    float*       lw = wl + (lane >> 2) * PITCH + scol;
    // LDS read: lane reads its own row (global row b0+lane == b)
    const float* lr = wl + lane * PITCH;

    float4 sv[4], sd[4], sy[4];           // one chunk in flight (48 VGPRs)

    auto issue_loads = [&](int k) {
        #pragma unroll
        for (int i = 0; i < 4; ++i) {
            sv[i] = *(const float4*)(gv + (size_t)i * 16 * LHIST + k * CH);
            sd[i] = *(const float4*)(gd + (size_t)i * 16 * LHIST + k * CH);
            sy[i] = *(const float4*)(gy + (size_t)i * 16 * LHIST + k * CH);
        }
    };
    auto write_stage = [&]() {
        #pragma unroll
        for (int i = 0; i < 4; ++i) {
            *(float4*)(lw + 0 * TILE + i * 16 * PITCH) = sv[i];
            *(float4*)(lw + 1 * TILE + i * 16 * PITCH) = sd[i];
            *(float4*)(lw + 2 * TILE + i * 16 * PITCH) = sy[i];
        }
    };

    // rolling v-carry: vp1 = v[t'-1], vp2 = v[t'-2]; step t' does
    // predict(v[t'-1], v[t'-1]-v[t'-2], dt[t']); update(y[t'])  (t' = t+1)
    float vp1 = 0.0f, vp2 = 0.0f;

    auto do_group = [&](int g) {            // 4 steps from LDS group g
        float4 v4 = *(const float4*)(lr + 0 * TILE + g * 4);
        float4 d4 = *(const float4*)(lr + 1 * TILE + g * 4);
        float4 y4 = *(const float4*)(lr + 2 * TILE + g * 4);
        const float* vv = (const float*)&v4;
        const float* dd = (const float*)&d4;
        const float* yy = (const float*)&y4;
        #pragma unroll
        for (int m = 0; m < 4; ++m) {
            float vcur = vv[m];
            predict(vp1, vp1 - vp2, dd[m]);
            update(yy[m]);
            vp2 = vp1; vp1 = vcur;
        }
    };

    // ---- prologue: chunk 0 staged, chunk 1 in flight ----
    issue_loads(0);
    write_stage();                           // per-load counted vmcnt (compiler)
    issue_loads(1);
    __builtin_amdgcn_sched_barrier(0);

    // ---- chunk 0: t' = 0 consumed as init (sx = y[0], dv(1)=0), then t'=1..15
    {
        float4 v4 = *(const float4*)(lr + 0 * TILE);
        float4 d4 = *(const float4*)(lr + 1 * TILE);
        float4 y4 = *(const float4*)(lr + 2 * TILE);
        const float* vv = (const float*)&v4;
        const float* dd = (const float*)&d4;
        const float* yy = (const float*)&y4;
        sx = yy[0]; vp1 = vv[0]; vp2 = vv[0];
        #pragma unroll
        for (int m = 1; m < 4; ++m) {
            float vcur = vv[m];
            predict(vp1, vp1 - vp2, dd[m]);
            update(yy[m]);
            vp2 = vp1; vp1 = vcur;
        }
        #pragma unroll
        for (int g = 1; g < 4; ++g) do_group(g);
    }

    // ---- chunks 1..6: drain in-flight into LDS, issue next, compute ----
    #pragma unroll 1
    for (int k = 1; k < 7; ++k) {
        write_stage();                       // waits chunk k's loads (counted)
        issue_loads(k + 1);                  // chunk k+1 streams under compute k
        __builtin_amdgcn_sched_barrier(0);   // the ONE pin: issue before compute
        #pragma unroll
        for (int g = 0; g < 4; ++g) do_group(g);
    }

    // ---- chunk 7: last history chunk, nothing left to prefetch ----
    {
        write_stage();
        #pragma unroll
        for (int g = 0; g < 4; ++g) do_group(g);
    }
    // history done: 127 predict/update pairs; vp1 = v_hist[b][127]

    // ---- future rollout: stream inputs/outputs directly, 4 steps per group.
    // No register staging arrays (r4's 52MB-spill lesson); compiler hoists
    // loads ahead as pressure allows (~50 regs live here, lots of room).
    const float4* vf4p = (const float4*)(v_fut  + (size_t)b * HFUT);
    const float4* df4p = (const float4*)(dt_fut + (size_t)b * HFUT);
    float4* xp = (float4*)(out + (size_t)b * HFUT);
    float4* xv = (float4*)(out + (size_t)BATCH * HFUT + (size_t)b * HFUT);
    float4* ue = (float4*)(out + 2 * (size_t)BATCH * HFUT + (size_t)b * HFUT);

    float vp = vp1;
    #pragma unroll
    for (int g = 0; g < HFUT / 4; ++g) {
        float4 v4 = vf4p[g];
        float4 d4 = df4p[g];
        const float* vv = (const float*)&v4;
        const float* dd = (const float*)&d4;
        float4 ox, ov, ou;
        float* oxp = (float*)&ox; float* ovp = (float*)&ov; float* oup = (float*)&ou;
        #pragma unroll
        for (int m = 0; m < 4; ++m) {
            predict(vv[m], vv[m] - vp, dd[m]);
            vp = vv[m];
            oxp[m] = sx; ovp[m] = p00; oup[m] = su;
        }
        xp[g] = ox; xv[g] = ov; ue[g] = ou;
    }
}

extern "C" void kernel_launch(void* const* d_in, const int* in_sizes, int n_in,
                              void* d_out, int out_size, void* d_ws, size_t ws_size,
                              hipStream_t stream) {
    const float* v_hist  = (const float*)d_in[0];
    const float* dt_hist = (const float*)d_in[1];
    const float* x_obs   = (const float*)d_in[2];
    const float* v_fut   = (const float*)d_in[3];
    const float* dt_fut  = (const float*)d_in[4];
    const float* theta   = (const float*)d_in[5];
    float* out = (float*)d_out;

    dim3 grid(BATCH / 256), block(256);
    hipLaunchKernelGGL(kalman_fwd, grid, block, 0, stream,
                       v_hist, dt_hist, x_obs, v_fut, dt_fut, theta, out);
}